// Round 16
// baseline (280.208 us; speedup 1.0000x reference)
//
#include <hip/hip_runtime.h>
#include <math.h>

#define NROWS 65536
#define DDIM 2048
#define NEXP 64
#define TOPK 8

constexpr int NSTEP = 64;        // k-steps of 32
constexpr float THR = 3e-4f;     // ambiguity gap threshold (split-bf16 err rms ~4e-6)
constexpr int WFRAG_STEP = 4096; // shorts per k-step: [hl 2][ct 4][lane 64][j 8]
constexpr int CAP = 16384;       // flagged-row list capacity (expect ~2300)

typedef short bf16x8 __attribute__((ext_vector_type(8)));
typedef float f32x4 __attribute__((ext_vector_type(4)));

__device__ inline unsigned short bfround(float f) {
    union { float f; unsigned u; } v; v.f = f;
    unsigned r = (v.u + 0x7fffu + ((v.u >> 16) & 1u)) >> 16;   // RNE
    return (unsigned short)r;
}
__device__ inline float bf2f(unsigned short h) {
    union { unsigned u; float f; } v; v.u = ((unsigned)h) << 16;
    return v.f;
}
__device__ inline void cvt8(const float4& A, const float4& B, bf16x8& h, bf16x8& l) {
    float f[8] = {A.x, A.y, A.z, A.w, B.x, B.y, B.z, B.w};
#pragma unroll
    for (int j = 0; j < 8; ++j) {
        unsigned short hh = bfround(f[j]);
        h[j] = (short)hh;
        l[j] = (short)bfround(f[j] - bf2f(hh));
    }
}

// One-shot: W fp32 [64][2048] -> bf16 hi/lo in MFMA B-fragment order.
__global__ __launch_bounds__(256)
void prep_kernel(const float* __restrict__ W, short* __restrict__ wfrag)
{
    const int t = blockIdx.x;           // 0..63
    const int tid = threadIdx.x;
    const int ct = tid >> 6, lane = tid & 63;
    const int e = ct * 16 + (lane & 15);
    const int k = t * 32 + (lane >> 4) * 8;
    const float* wp = W + (size_t)e * DDIM + k;
    float4 a = *reinterpret_cast<const float4*>(wp);
    float4 b = *reinterpret_cast<const float4*>(wp + 4);
    bf16x8 h, l;
    cvt8(a, b, h, l);
    short* base = wfrag + (size_t)t * WFRAG_STEP;
    *reinterpret_cast<bf16x8*>(base + (ct * 64 + lane) * 8) = h;          // hl=0
    *reinterpret_cast<bf16x8*>(base + 2048 + (ct * 64 + lane) * 8) = l;   // hl=1
}

// Split-bf16 MFMA GEMM (byte-identical to r13/r15; measured 153.6 us).
__global__ __launch_bounds__(256, 2)
void gemm_kernel(const float* __restrict__ x, const short* __restrict__ wfrag,
                 float* __restrict__ logits)
{
    __shared__ __align__(16) short Bfrag[2][2][4][64][8];   // 16 KB

    const int tid = threadIdx.x;
    const int w = tid >> 6;
    const int lane = tid & 63;
    const int g = lane >> 4;
    const int c = lane & 15;
    const int row0 = blockIdx.x * 64 + w * 16;
    const float* xr = x + (size_t)(row0 + c) * DDIM + g * 8;

    const int se = tid >> 2, skg = tid & 3;
    const int sct = se >> 4;
    const int slane = (se & 15) + (skg << 4);
    const int soff = (sct * 64 + slane) * 8;

    auto stageB = [&](int t, int buf) {
        const short* src = wfrag + (size_t)t * WFRAG_STEP + soff;
        *reinterpret_cast<bf16x8*>(&Bfrag[buf][0][sct][slane][0]) =
            *reinterpret_cast<const bf16x8*>(src);
        *reinterpret_cast<bf16x8*>(&Bfrag[buf][1][sct][slane][0]) =
            *reinterpret_cast<const bf16x8*>(src + 2048);
    };

    f32x4 acc[4];
#pragma unroll
    for (int ct = 0; ct < 4; ++ct) acc[ct] = (f32x4){0.f, 0.f, 0.f, 0.f};

    float4 xa0 = *reinterpret_cast<const float4*>(xr);
    float4 xa1 = *reinterpret_cast<const float4*>(xr + 4);
    float4 xb0, xb1;
    stageB(0, 0);
    __syncthreads();

    for (int t = 0; t < NSTEP; ++t) {
        const int buf = t & 1;
        const int kn = (t + 1) * 32;
        if (t + 1 < NSTEP) {
            xb0 = *reinterpret_cast<const float4*>(xr + kn);
            xb1 = *reinterpret_cast<const float4*>(xr + kn + 4);
            stageB(t + 1, buf ^ 1);
        }
        bf16x8 ah, al;
        cvt8(xa0, xa1, ah, al);
#pragma unroll
        for (int ct = 0; ct < 4; ++ct) {
            bf16x8 bh = *reinterpret_cast<const bf16x8*>(&Bfrag[buf][0][ct][lane][0]);
            bf16x8 bl = *reinterpret_cast<const bf16x8*>(&Bfrag[buf][1][ct][lane][0]);
            acc[ct] = __builtin_amdgcn_mfma_f32_16x16x32_bf16(ah, bh, acc[ct], 0, 0, 0);
            acc[ct] = __builtin_amdgcn_mfma_f32_16x16x32_bf16(ah, bl, acc[ct], 0, 0, 0);
            acc[ct] = __builtin_amdgcn_mfma_f32_16x16x32_bf16(al, bh, acc[ct], 0, 0, 0);
        }
        xa0 = xb0; xa1 = xb1;
        __syncthreads();
    }

#pragma unroll
    for (int ct = 0; ct < 4; ++ct)
#pragma unroll
        for (int reg = 0; reg < 4; ++reg)
            logits[(size_t)(row0 + g * 4 + reg) * NEXP + ct * 16 + c] = acc[ct][reg];
}

// Epilogue v4 (THIN): width-16 groups, 4 rows/wave in parallel, fast-math exp.
// No fp64 path in this kernel (r15 post-mortem: the fat cold path inflates
// hot-loop VGPR allocation; libm expf is ~27 instr). Flagged rows -> global
// list; fixup_kernel handles them (and their freq counts).
__global__ __launch_bounds__(256, 2)
void epilogue_kernel(const float* __restrict__ logits,
                     float* __restrict__ out_idx, float* __restrict__ out_gate,
                     float* __restrict__ g_psum, float* __restrict__ g_freq,
                     float* __restrict__ g_zsum, int* __restrict__ g_cnt,
                     int* __restrict__ g_rows)
{
    __shared__ float psum_s[NEXP];
    __shared__ float fcnt_s[NEXP];
    __shared__ float zsq_s;
    const int tid = threadIdx.x;
    const int w = tid >> 6;
    const int lane = tid & 63;
    const int g = lane >> 4;         // row sub-id within wave-iteration
    const int c = lane & 15;         // expert quad id: owns experts 4c..4c+3
    if (tid < NEXP) { psum_s[tid] = 0.f; fcnt_s[tid] = 0.f; }
    if (tid == 0) zsq_s = 0.f;
    __syncthreads();

    const int wi = blockIdx.x * 4 + w;   // wave id 0..8191 -> rows wi*8..wi*8+7
    float pcol[4] = {0.f, 0.f, 0.f, 0.f};
    float zacc = 0.f;

    for (int it = 0; it < 2; ++it) {
        const int row = wi * 8 + it * 4 + g;
        float4 Lv = *reinterpret_cast<const float4*>(&logits[(size_t)row * NEXP + c * 4]);
        float L[4] = {Lv.x, Lv.y, Lv.z, Lv.w};
        float ld[4] = {L[0], L[1], L[2], L[3]};

        float tv[9]; int ti[9];
#pragma unroll
        for (int p = 0; p < 9; ++p) {    // top-8 + rank-9 (gap test)
            float bv = -3.4e38f; int bgi = 127;
#pragma unroll
            for (int j = 0; j < 4; ++j) {
                int e = c * 4 + j;
                if (ld[j] > bv) { bv = ld[j]; bgi = e; }
            }
#pragma unroll
            for (int m = 1; m < 16; m <<= 1) {   // width-16: stays in group
                float ov = __shfl_xor(bv, m, 16);
                int ogi = __shfl_xor(bgi, m, 16);
                if (ov > bv || (ov == bv && ogi < bgi)) { bv = ov; bgi = ogi; }
            }
            tv[p] = bv; ti[p] = bgi;
#pragma unroll
            for (int j = 0; j < 4; ++j)          // winner clears (static idx)
                if (bgi == c * 4 + j) ld[j] = -3.4e38f;
        }

        // softmax probs (psum): lane owns experts 4c..4c+3 -> register-local
        const float m0 = tv[0];
        float pe[4], ps = 0.f;
#pragma unroll
        for (int j = 0; j < 4; ++j) { pe[j] = __expf(L[j] - m0); ps += pe[j]; }
        float s = ps;
#pragma unroll
        for (int m = 1; m < 16; m <<= 1) s += __shfl_xor(s, m, 16);
        const float inv_s = 1.f / s;
#pragma unroll
        for (int j = 0; j < 4; ++j) pcol[j] += pe[j] * inv_s;

        if (c == 0) {   // z-loss: logaddexp(lse, log(1e-5))^2
            float lsef = m0 + __logf(s);
            const float lb = -11.512925464970229f;
            float mx = fmaxf(lsef, lb), mn = fminf(lsef, lb);
            float z = mx + log1pf(__expf(mn - mx));
            zacc += z * z;
        }

        float mg = 3.4e38f;
#pragma unroll
        for (int p = 0; p < 8; ++p) mg = fminf(mg, tv[p] - tv[p + 1]);
        const bool flagged = (mg < THR);    // group-uniform (tv post-reduce)
        const size_t base = (size_t)row * TOPK;

        // gates: gs lane-local (all lanes hold tv[]), lane c<8 writes rank c
        float gs = 0.f;
#pragma unroll
        for (int p = 0; p < 8; ++p) gs += __expf(tv[p] - m0);
        if (c < 8) {
            float mytv = tv[0]; int myti = ti[0];
#pragma unroll
            for (int p = 1; p < 8; ++p)
                if (c == p) { mytv = tv[p]; myti = ti[p]; }
            out_idx[base + c] = (float)myti;
            out_gate[base + c] = __expf(mytv - m0) / gs;
            if (!flagged) atomicAdd(&fcnt_s[myti], 1.f);
        }
        if (flagged && c == 0) {            // defer to fixup kernel
            int idx = atomicAdd(g_cnt, 1);
            if (idx < CAP) g_rows[idx] = row;
        }
    }

    // block tallies -> one global atomic per expert per block
#pragma unroll
    for (int j = 0; j < 4; ++j) atomicAdd(&psum_s[c * 4 + j], pcol[j]);
    if (c == 0) atomicAdd(&zsq_s, zacc);
    __syncthreads();
    if (tid < NEXP) {
        atomicAdd(&g_psum[tid], psum_s[tid]);
        atomicAdd(&g_freq[tid], fcnt_s[tid]);
    }
    if (tid == 0) atomicAdd(g_zsum, zsq_s);
}

// fp64 recheck of flagged rows (one wave per row): bitonic on fp32 logits
// (from d_ws) for v9 cutoff, coalesced fp64 dots over candidates, exact
// top-8 + gates + deferred freq counts. r13 machinery verbatim.
__global__ __launch_bounds__(256, 1)
void fixup_kernel(const float* __restrict__ x, const float* __restrict__ W,
                  const float* __restrict__ logits,
                  float* __restrict__ out_idx, float* __restrict__ out_gate,
                  float* __restrict__ g_freq,
                  const int* __restrict__ g_cnt, const int* __restrict__ g_rows)
{
    const int n = min(*g_cnt, CAP);
    const int lane = threadIdx.x & 63;
    const int wid = (blockIdx.x * blockDim.x + threadIdx.x) >> 6;
    const int nw = (gridDim.x * blockDim.x) >> 6;

    for (int i = wid; i < n; i += nw) {
        const int row = g_rows[i];
        const float lg = logits[(size_t)row * NEXP + lane];

        unsigned u = __float_as_uint(lg);
        unsigned ordb = (u & 0x80000000u) ? ~u : (u | 0x80000000u);
        unsigned long long key =
            ((unsigned long long)ordb << 32) | (unsigned)(63 - lane);
#pragma unroll
        for (int k = 2; k <= 64; k <<= 1) {
#pragma unroll
            for (int j = k >> 1; j > 0; j >>= 1) {
                unsigned long long other = __shfl_xor(key, j, 64);
                const bool keep_max = ((lane & j) == 0) == ((lane & k) == 0);
                const bool mine_bigger = key > other;
                key = (keep_max == mine_bigger) ? key : other;
            }
        }
        unsigned ou = (unsigned)(key >> 32);
        unsigned ub = (ou & 0x80000000u) ? (ou ^ 0x80000000u) : ~ou;
        const float val = __uint_as_float(ub);
        const float v9 = __shfl(val, 8, 64);

        const bool cand = (lg >= v9 - THR);
        unsigned long long cm = __ballot(cand);
        const float* xrw = x + (size_t)row * DDIM;
        float4 xv[8];
#pragma unroll
        for (int j = 0; j < 8; ++j)
            xv[j] = *reinterpret_cast<const float4*>(xrw + j * 256 + lane * 4);

        double myD = -HUGE_VAL;
        unsigned long long m2 = cm;
        while (m2) {                        // serial coalesced fp64 dots
            const int e = (int)__ffsll((unsigned long long)m2) - 1;
            m2 &= (m2 - 1);
            const float* wrp = W + (size_t)e * DDIM;
            double p0 = 0.0, p1 = 0.0, p2 = 0.0, p3 = 0.0;
#pragma unroll
            for (int j = 0; j < 8; ++j) {
                float4 wv = *reinterpret_cast<const float4*>(wrp + j * 256 + lane * 4);
                p0 = fma((double)xv[j].x, (double)wv.x, p0);
                p1 = fma((double)xv[j].y, (double)wv.y, p1);
                p2 = fma((double)xv[j].z, (double)wv.z, p2);
                p3 = fma((double)xv[j].w, (double)wv.w, p3);
            }
            double sd = (p0 + p1) + (p2 + p3);
#pragma unroll
            for (int m = 1; m < 64; m <<= 1) sd += __shfl_xor(sd, m, 64);
            if (lane == e) myD = sd;
        }

        double v = cand ? myD : -HUGE_VAL;
        double tvd[8]; int ti8[8];
#pragma unroll
        for (int p = 0; p < 8; ++p) {
            double bv = v; int bgi = lane;
#pragma unroll
            for (int m = 1; m < 64; m <<= 1) {
                double ov = __shfl_xor(bv, m, 64);
                int ogi = __shfl_xor(bgi, m, 64);
                if (ov > bv || (ov == bv && ogi < bgi)) { bv = ov; bgi = ogi; }
            }
            tvd[p] = bv; ti8[p] = bgi;
            if (lane == bgi) v = -HUGE_VAL;
        }
        const double m0d = tvd[0];
        double gsum = 0.0, ge[8];
#pragma unroll
        for (int j = 0; j < 8; ++j) { ge[j] = exp(tvd[j] - m0d); gsum += ge[j]; }
        if (lane < 8) {
            double myge = ge[0]; int myti = ti8[0];
#pragma unroll
            for (int j = 1; j < 8; ++j)
                if (lane == j) { myge = ge[j]; myti = ti8[j]; }
            const size_t base = (size_t)row * TOPK;
            out_idx[base + lane] = (float)myti;
            out_gate[base + lane] = (float)(myge / gsum);
            atomicAdd(&g_freq[myti], 1.0f);   // deferred freq for flagged rows
        }
    }
}

__global__ void finalize_kernel(const float* __restrict__ g_psum,
                                const float* __restrict__ g_freq,
                                const float* __restrict__ g_zsum,
                                float* __restrict__ out_loss)
{
    const int lane = threadIdx.x & 63;
    float p = g_psum[lane], f = g_freq[lane];
    float sp = p, sf = f;
#pragma unroll
    for (int m = 1; m < 64; m <<= 1) { sp += __shfl_xor(sp, m, 64); sf += __shfl_xor(sf, m, 64); }
    sp = fmaxf(sp, 1e-12f);
    sf = fmaxf(sf, 1e-12f);
    float term = (p / sp) * (f / sf);
#pragma unroll
    for (int m = 1; m < 64; m <<= 1) term += __shfl_xor(term, m, 64);
    if (lane == 0)
        out_loss[0] = (float)NEXP * term + 0.1f * (g_zsum[0] / (float)NROWS);
}

extern "C" void kernel_launch(void* const* d_in, const int* in_sizes, int n_in,
                              void* d_out, int out_size, void* d_ws, size_t ws_size,
                              hipStream_t stream)
{
    const float* x = (const float*)d_in[0];
    const float* W = (const float*)d_in[1];
    float* out = (float*)d_out;
    float* out_idx  = out;                            // [65536*8] indices as float
    float* out_gate = out + (size_t)NROWS * TOPK;     // [65536*8] gates
    float* out_loss = out + (size_t)2 * NROWS * TOPK; // [1] loss

    // ws layout (floats): [0..63] psum | [64..127] freq | [128] zsum |
    //   [129] cnt(int) | [130..130+CAP) rows | [32768..) logits 65536x64 |
    //   then wfrag (512 KB, 16B-aligned)
    float* acc    = (float*)d_ws;
    int*   cnt    = (int*)d_ws + 129;
    int*   rows   = (int*)d_ws + 130;
    float* logits = (float*)d_ws + 32768;
    short* wfrag  = (short*)((float*)d_ws + 32768 + (size_t)NROWS * NEXP);
    hipMemsetAsync(d_ws, 0, 132 * sizeof(float), stream);

    prep_kernel<<<NSTEP, 256, 0, stream>>>(W, wfrag);
    gemm_kernel<<<NROWS / 64, 256, 0, stream>>>(x, wfrag, logits);
    epilogue_kernel<<<2048, 256, 0, stream>>>(logits, out_idx, out_gate,
                                              acc, acc + NEXP, acc + 2 * NEXP,
                                              cnt, rows);
    fixup_kernel<<<512, 256, 0, stream>>>(x, W, logits, out_idx, out_gate,
                                          acc + NEXP, cnt, rows);
    finalize_kernel<<<1, 64, 0, stream>>>(acc, acc + NEXP, acc + 2 * NEXP, out_loss);
}

// Round 17
// 244.204 us; speedup vs baseline: 1.1474x; 1.1474x over previous
//
#include <hip/hip_runtime.h>
#include <math.h>

#define NROWS 65536
#define DDIM 2048
#define NEXP 64
#define TOPK 8

constexpr int NSTEP = 64;        // k-steps of 32
constexpr float THR = 3e-4f;     // ambiguity gap threshold (split-bf16 err rms ~4e-6)
constexpr int WFRAG_STEP = 4096; // shorts per k-step: [hl 2][ct 4][lane 64][j 8]
constexpr int CAP = 16384;       // flagged-row list capacity (expect ~2300)

typedef short bf16x8 __attribute__((ext_vector_type(8)));
typedef float f32x4 __attribute__((ext_vector_type(4)));

__device__ inline unsigned short bfround(float f) {
    union { float f; unsigned u; } v; v.f = f;
    unsigned r = (v.u + 0x7fffu + ((v.u >> 16) & 1u)) >> 16;   // RNE
    return (unsigned short)r;
}
__device__ inline float bf2f(unsigned short h) {
    union { unsigned u; float f; } v; v.u = ((unsigned)h) << 16;
    return v.f;
}
__device__ inline void cvt8(const float4& A, const float4& B, bf16x8& h, bf16x8& l) {
    float f[8] = {A.x, A.y, A.z, A.w, B.x, B.y, B.z, B.w};
#pragma unroll
    for (int j = 0; j < 8; ++j) {
        unsigned short hh = bfround(f[j]);
        h[j] = (short)hh;
        l[j] = (short)bfround(f[j] - bf2f(hh));
    }
}

// One-shot: W fp32 [64][2048] -> bf16 hi/lo in MFMA B-fragment order.
__global__ __launch_bounds__(256)
void prep_kernel(const float* __restrict__ W, short* __restrict__ wfrag)
{
    const int t = blockIdx.x;           // 0..63
    const int tid = threadIdx.x;
    const int ct = tid >> 6, lane = tid & 63;
    const int e = ct * 16 + (lane & 15);
    const int k = t * 32 + (lane >> 4) * 8;
    const float* wp = W + (size_t)e * DDIM + k;
    float4 a = *reinterpret_cast<const float4*>(wp);
    float4 b = *reinterpret_cast<const float4*>(wp + 4);
    bf16x8 h, l;
    cvt8(a, b, h, l);
    short* base = wfrag + (size_t)t * WFRAG_STEP;
    *reinterpret_cast<bf16x8*>(base + (ct * 64 + lane) * 8) = h;          // hl=0
    *reinterpret_cast<bf16x8*>(base + 2048 + (ct * 64 + lane) * 8) = l;   // hl=1
}

// FUSED gemm+epilogue. r16 post-mortem: split kernels serialize the ~154us
// memory-bound K-loop and ~95us VALU/shfl-bound epilogue at the graph edge;
// fused blocks at different phases overlap the two pipes on a CU (m114).
// K-loop = r13's measured 153.6us structure, byte-equivalent. Epilogue =
// width-16 machinery on acc directly (expert = ct*16+c), THIN: fp64 recheck
// deferred to fixup_kernel (keeps VGPR under the (256,2)=128 cap).
__global__ __launch_bounds__(256, 2)
void fused_kernel(const float* __restrict__ x, const short* __restrict__ wfrag,
                  float* __restrict__ out_idx, float* __restrict__ out_gate,
                  float* __restrict__ g_psum, float* __restrict__ g_freq,
                  float* __restrict__ g_zsum, int* __restrict__ g_cnt,
                  int* __restrict__ g_rows, float* __restrict__ g_logits)
{
    __shared__ __align__(16) short Bfrag[2][2][4][64][8];   // 16 KB
    __shared__ float psum_s[NEXP];
    __shared__ float fcnt_s[NEXP];
    __shared__ float zsq_s;

    const int tid = threadIdx.x;
    const int w = tid >> 6;
    const int lane = tid & 63;
    const int g = lane >> 4;         // k-subgroup (A) / row subgroup (C)
    const int c = lane & 15;         // A row offset / C col offset
    const int row0 = blockIdx.x * 64 + w * 16;
    const float* xr = x + (size_t)(row0 + c) * DDIM + g * 8;

    if (tid < NEXP) { psum_s[tid] = 0.f; fcnt_s[tid] = 0.f; }
    if (tid == 0) zsq_s = 0.f;

    const int se = tid >> 2, skg = tid & 3;
    const int sct = se >> 4;
    const int slane = (se & 15) + (skg << 4);
    const int soff = (sct * 64 + slane) * 8;

    auto stageB = [&](int t, int buf) {
        const short* src = wfrag + (size_t)t * WFRAG_STEP + soff;
        *reinterpret_cast<bf16x8*>(&Bfrag[buf][0][sct][slane][0]) =
            *reinterpret_cast<const bf16x8*>(src);
        *reinterpret_cast<bf16x8*>(&Bfrag[buf][1][sct][slane][0]) =
            *reinterpret_cast<const bf16x8*>(src + 2048);
    };

    f32x4 acc[4];
#pragma unroll
    for (int ct = 0; ct < 4; ++ct) acc[ct] = (f32x4){0.f, 0.f, 0.f, 0.f};

    float4 xa0 = *reinterpret_cast<const float4*>(xr);
    float4 xa1 = *reinterpret_cast<const float4*>(xr + 4);
    float4 xb0, xb1;
    stageB(0, 0);
    __syncthreads();                 // also covers psum_s/fcnt_s/zsq_s init

    for (int t = 0; t < NSTEP; ++t) {
        const int buf = t & 1;
        const int kn = (t + 1) * 32;
        if (t + 1 < NSTEP) {
            xb0 = *reinterpret_cast<const float4*>(xr + kn);
            xb1 = *reinterpret_cast<const float4*>(xr + kn + 4);
            stageB(t + 1, buf ^ 1);
        }
        bf16x8 ah, al;
        cvt8(xa0, xa1, ah, al);
        // 3-term split-bf16: x*w = xh*wh + xh*wl + xl*wh (xl*wl ~4e-6, dropped)
#pragma unroll
        for (int ct = 0; ct < 4; ++ct) {
            bf16x8 bh = *reinterpret_cast<const bf16x8*>(&Bfrag[buf][0][ct][lane][0]);
            bf16x8 bl = *reinterpret_cast<const bf16x8*>(&Bfrag[buf][1][ct][lane][0]);
            acc[ct] = __builtin_amdgcn_mfma_f32_16x16x32_bf16(ah, bh, acc[ct], 0, 0, 0);
            acc[ct] = __builtin_amdgcn_mfma_f32_16x16x32_bf16(ah, bl, acc[ct], 0, 0, 0);
            acc[ct] = __builtin_amdgcn_mfma_f32_16x16x32_bf16(al, bh, acc[ct], 0, 0, 0);
        }
        xa0 = xb0; xa1 = xb1;
        __syncthreads();
    }

    // ---- fused epilogue ----
    // C/D layout (m89): acc[ct][reg] = C[row0 + g*4 + reg][ct*16 + c].
    // 16 lanes sharing g hold a row's 64 experts: lane c owns {ct*16+c}.
    float pcol[4] = {0.f, 0.f, 0.f, 0.f};
    float zacc = 0.f;

#pragma unroll
    for (int reg = 0; reg < 4; ++reg) {
        const int row = row0 + g * 4 + reg;
        float ld[4];
#pragma unroll
        for (int ct = 0; ct < 4; ++ct) ld[ct] = acc[ct][reg];

        float tv[9]; int ti[9];
#pragma unroll
        for (int p = 0; p < 9; ++p) {    // top-8 + rank-9 (gap test)
            float bv = -3.4e38f; int bgi = 127;
#pragma unroll
            for (int ct = 0; ct < 4; ++ct) {
                int e = ct * 16 + c;
                if (ld[ct] > bv) { bv = ld[ct]; bgi = e; }
            }
#pragma unroll
            for (int m = 1; m < 16; m <<= 1) {   // width-16: stays in g-group
                float ov = __shfl_xor(bv, m, 16);
                int ogi = __shfl_xor(bgi, m, 16);
                if (ov > bv || (ov == bv && ogi < bgi)) { bv = ov; bgi = ogi; }
            }
            tv[p] = bv; ti[p] = bgi;
#pragma unroll
            for (int ct = 0; ct < 4; ++ct)       // winner clears (static idx)
                if (bgi == ct * 16 + c) ld[ct] = -3.4e38f;
        }

        // softmax probs (psum): lane owns experts ct*16+c -> register-local
        const float m0 = tv[0];
        float pe[4], ps = 0.f;
#pragma unroll
        for (int ct = 0; ct < 4; ++ct) {
            pe[ct] = __expf(acc[ct][reg] - m0);
            ps += pe[ct];
        }
        float s = ps;
#pragma unroll
        for (int m = 1; m < 16; m <<= 1) s += __shfl_xor(s, m, 16);
        const float inv_s = 1.f / s;
#pragma unroll
        for (int ct = 0; ct < 4; ++ct) pcol[ct] += pe[ct] * inv_s;

        if (c == 0) {   // z-loss: logaddexp(lse, log(1e-5))^2
            float lsef = m0 + __logf(s);
            const float lb = -11.512925464970229f;
            float mx = fmaxf(lsef, lb), mn = fminf(lsef, lb);
            float z = mx + log1pf(__expf(mn - mx));
            zacc += z * z;
        }

        float mg = 3.4e38f;
#pragma unroll
        for (int p = 0; p < 8; ++p) mg = fminf(mg, tv[p] - tv[p + 1]);
        const bool flagged = (mg < THR);    // group-uniform (tv post-reduce)
        const size_t base = (size_t)row * TOPK;

        // gates: gs lane-local (all lanes hold tv[]), lane c<8 writes rank c
        float gs = 0.f;
#pragma unroll
        for (int p = 0; p < 8; ++p) gs += __expf(tv[p] - m0);
        if (c < 8) {
            float mytv = tv[0]; int myti = ti[0];
#pragma unroll
            for (int p = 1; p < 8; ++p)
                if (c == p) { mytv = tv[p]; myti = ti[p]; }
            out_idx[base + c] = (float)myti;
            out_gate[base + c] = __expf(mytv - m0) / gs;
            if (!flagged) atomicAdd(&fcnt_s[myti], 1.f);
        }
        if (flagged) {                      // dump row logits for fixup
            int idx = 0;
            if (c == 0) idx = atomicAdd(g_cnt, 1);
            idx = __shfl(idx, (lane >> 4) << 4, 64);   // bcast from c==0 lane
            if (idx < CAP) {
                if (c == 0) g_rows[idx] = row;
#pragma unroll
                for (int ct = 0; ct < 4; ++ct)
                    g_logits[(size_t)idx * NEXP + ct * 16 + c] = acc[ct][reg];
            }
        }
    }

    // block tallies -> one global atomic per expert per block
#pragma unroll
    for (int ct = 0; ct < 4; ++ct) atomicAdd(&psum_s[ct * 16 + c], pcol[ct]);
    if (c == 0) atomicAdd(&zsq_s, zacc);
    __syncthreads();
    if (tid < NEXP) {
        atomicAdd(&g_psum[tid], psum_s[tid]);
        atomicAdd(&g_freq[tid], fcnt_s[tid]);
    }
    if (tid == 0) atomicAdd(g_zsum, zsq_s);
}

// fp64 recheck of flagged rows (one wave per row): bitonic on the DUMPED
// fp32 logits for v9 cutoff, coalesced fp64 dots over candidates, exact
// top-8 + gates + deferred freq counts. r16 machinery, g_logits source.
__global__ __launch_bounds__(256, 1)
void fixup_kernel(const float* __restrict__ x, const float* __restrict__ W,
                  float* __restrict__ out_idx, float* __restrict__ out_gate,
                  float* __restrict__ g_freq,
                  const int* __restrict__ g_cnt, const int* __restrict__ g_rows,
                  const float* __restrict__ g_logits)
{
    const int n = min(*g_cnt, CAP);
    const int lane = threadIdx.x & 63;
    const int wid = (blockIdx.x * blockDim.x + threadIdx.x) >> 6;
    const int nw = (gridDim.x * blockDim.x) >> 6;

    for (int i = wid; i < n; i += nw) {
        const int row = g_rows[i];
        const float lg = g_logits[(size_t)i * NEXP + lane];

        unsigned u = __float_as_uint(lg);
        unsigned ordb = (u & 0x80000000u) ? ~u : (u | 0x80000000u);
        unsigned long long key =
            ((unsigned long long)ordb << 32) | (unsigned)(63 - lane);
#pragma unroll
        for (int k = 2; k <= 64; k <<= 1) {
#pragma unroll
            for (int j = k >> 1; j > 0; j >>= 1) {
                unsigned long long other = __shfl_xor(key, j, 64);
                const bool keep_max = ((lane & j) == 0) == ((lane & k) == 0);
                const bool mine_bigger = key > other;
                key = (keep_max == mine_bigger) ? key : other;
            }
        }
        unsigned ou = (unsigned)(key >> 32);
        unsigned ub = (ou & 0x80000000u) ? (ou ^ 0x80000000u) : ~ou;
        const float val = __uint_as_float(ub);
        const float v9 = __shfl(val, 8, 64);

        const bool cand = (lg >= v9 - THR);
        unsigned long long cm = __ballot(cand);
        const float* xrw = x + (size_t)row * DDIM;
        float4 xv[8];
#pragma unroll
        for (int j = 0; j < 8; ++j)
            xv[j] = *reinterpret_cast<const float4*>(xrw + j * 256 + lane * 4);

        double myD = -HUGE_VAL;
        unsigned long long m2 = cm;
        while (m2) {                        // serial coalesced fp64 dots
            const int e = (int)__ffsll((unsigned long long)m2) - 1;
            m2 &= (m2 - 1);
            const float* wrp = W + (size_t)e * DDIM;
            double p0 = 0.0, p1 = 0.0, p2 = 0.0, p3 = 0.0;
#pragma unroll
            for (int j = 0; j < 8; ++j) {
                float4 wv = *reinterpret_cast<const float4*>(wrp + j * 256 + lane * 4);
                p0 = fma((double)xv[j].x, (double)wv.x, p0);
                p1 = fma((double)xv[j].y, (double)wv.y, p1);
                p2 = fma((double)xv[j].z, (double)wv.z, p2);
                p3 = fma((double)xv[j].w, (double)wv.w, p3);
            }
            double sd = (p0 + p1) + (p2 + p3);
#pragma unroll
            for (int m = 1; m < 64; m <<= 1) sd += __shfl_xor(sd, m, 64);
            if (lane == e) myD = sd;
        }

        double v = cand ? myD : -HUGE_VAL;
        double tvd[8]; int ti8[8];
#pragma unroll
        for (int p = 0; p < 8; ++p) {
            double bv = v; int bgi = lane;
#pragma unroll
            for (int m = 1; m < 64; m <<= 1) {
                double ov = __shfl_xor(bv, m, 64);
                int ogi = __shfl_xor(bgi, m, 64);
                if (ov > bv || (ov == bv && ogi < bgi)) { bv = ov; bgi = ogi; }
            }
            tvd[p] = bv; ti8[p] = bgi;
            if (lane == bgi) v = -HUGE_VAL;
        }
        const double m0d = tvd[0];
        double gsum = 0.0, ge[8];
#pragma unroll
        for (int j = 0; j < 8; ++j) { ge[j] = exp(tvd[j] - m0d); gsum += ge[j]; }
        if (lane < 8) {
            double myge = ge[0]; int myti = ti8[0];
#pragma unroll
            for (int j = 1; j < 8; ++j)
                if (lane == j) { myge = ge[j]; myti = ti8[j]; }
            const size_t base = (size_t)row * TOPK;
            out_idx[base + lane] = (float)myti;
            out_gate[base + lane] = (float)(myge / gsum);
            atomicAdd(&g_freq[myti], 1.0f);   // deferred freq for flagged rows
        }
    }
}

__global__ void finalize_kernel(const float* __restrict__ g_psum,
                                const float* __restrict__ g_freq,
                                const float* __restrict__ g_zsum,
                                float* __restrict__ out_loss)
{
    const int lane = threadIdx.x & 63;
    float p = g_psum[lane], f = g_freq[lane];
    float sp = p, sf = f;
#pragma unroll
    for (int m = 1; m < 64; m <<= 1) { sp += __shfl_xor(sp, m, 64); sf += __shfl_xor(sf, m, 64); }
    sp = fmaxf(sp, 1e-12f);
    sf = fmaxf(sf, 1e-12f);
    float term = (p / sp) * (f / sf);
#pragma unroll
    for (int m = 1; m < 64; m <<= 1) term += __shfl_xor(term, m, 64);
    if (lane == 0)
        out_loss[0] = (float)NEXP * term + 0.1f * (g_zsum[0] / (float)NROWS);
}

extern "C" void kernel_launch(void* const* d_in, const int* in_sizes, int n_in,
                              void* d_out, int out_size, void* d_ws, size_t ws_size,
                              hipStream_t stream)
{
    const float* x = (const float*)d_in[0];
    const float* W = (const float*)d_in[1];
    float* out = (float*)d_out;
    float* out_idx  = out;                            // [65536*8] indices as float
    float* out_gate = out + (size_t)NROWS * TOPK;     // [65536*8] gates
    float* out_loss = out + (size_t)2 * NROWS * TOPK; // [1] loss

    // ws layout (floats): [0..63] psum | [64..127] freq | [128] zsum |
    //   [129] cnt(int) | [130..130+CAP) rows | [16896..) flagged logits
    //   (CAP x 64 = 1M floats) | wfrag (512 KB, 16B-aligned) at 1065984
    float* acc      = (float*)d_ws;
    int*   cnt      = (int*)d_ws + 129;
    int*   rows     = (int*)d_ws + 130;
    float* g_logits = (float*)d_ws + 16896;
    short* wfrag    = (short*)((float*)d_ws + 1065984);
    hipMemsetAsync(d_ws, 0, 132 * sizeof(float), stream);

    prep_kernel<<<NSTEP, 256, 0, stream>>>(W, wfrag);
    fused_kernel<<<NROWS / 64, 256, 0, stream>>>(
        x, wfrag, out_idx, out_gate, acc, acc + NEXP, acc + 2 * NEXP,
        cnt, rows, g_logits);
    fixup_kernel<<<512, 256, 0, stream>>>(x, W, out_idx, out_gate, acc + NEXP,
                                          cnt, rows, g_logits);
    finalize_kernel<<<1, 64, 0, stream>>>(acc, acc + NEXP, acc + 2 * NEXP, out_loss);
}